// Round 6
// baseline (425.784 us; speedup 1.0000x reference)
//
#include <hip/hip_runtime.h>

#define N_SAMP 8192
#define D_DIM 6144
#define K_CLS 10
#define CHUNK 64                          // samples per block (natural order)
#define NWIN (N_SAMP / CHUNK)             // 128 windows
#define COLS_PER_BLOCK 1024               // 256 threads * 4 floats
#define NGROUPS (D_DIM / COLS_PER_BLOCK)  // 6 -> grid 768 = exactly 3 blocks/CU
#define PIPE 8                            // outstanding float4 loads per thread
#define ROWB (D_DIM * 4)                  // row stride in bytes (24576)

// Accumulation, natural sample order (pure sequential streaming reads).
// Per-class S1 lives in a 40 KB LDS table; each thread exclusively owns its 4
// columns for all 10 classes (no LDS atomics, b128 RMW, conflict-free).
// Class index is block-uniform per sample (readfirstlane -> scalar branch).
// S2 (column-reduced) accumulates in 10 per-thread registers via uniform
// branch select. Single flush at the end.
__global__ __launch_bounds__(256) void wcss_accum(const float* __restrict__ X,
                                                  const int* __restrict__ y,
                                                  float* __restrict__ S1,
                                                  float* __restrict__ s2sum) {
    __shared__ float s1l[K_CLS * COLS_PER_BLOCK];   // 40 KB
    __shared__ int ylds[CHUNK];
    __shared__ float wred[4];
    const int tid = threadIdx.x;
    const int lane = tid & 63;
    const int wid = tid >> 6;
    const int g = blockIdx.x;
    const int w = blockIdx.y;

    // zero LDS table (10 float4 per thread)
    float4* zp = (float4*)s1l;
#pragma unroll
    for (int j = 0; j < K_CLS; ++j)
        zp[j * 256 + tid] = make_float4(0.f, 0.f, 0.f, 0.f);
    if (tid < CHUNK) ylds[tid] = y[w * CHUNK + tid];
    __syncthreads();

    const char* basep =
        (const char*)(X + (size_t)w * CHUNK * D_DIM + g * COLS_PER_BLOCK + tid * 4);

    float4 buf[PIPE];
#pragma unroll
    for (int j = 0; j < PIPE; ++j)
        buf[j] = *(const float4*)(basep + (size_t)j * ROWB);

    float s2r[K_CLS];
#pragma unroll
    for (int k = 0; k < K_CLS; ++k) s2r[k] = 0.f;

#pragma unroll
    for (int s = 0; s < CHUNK; ++s) {
        const float4 v = buf[s & (PIPE - 1)];
        if (s + PIPE < CHUNK)   // compile-time after full unroll
            buf[s & (PIPE - 1)] =
                *(const float4*)(basep + (size_t)(s + PIPE) * ROWB);

        const int ks = __builtin_amdgcn_readfirstlane(ylds[s]);

        // S1 += v in the class's LDS row (exclusive per-thread cells)
        float4* cell = (float4*)&s1l[ks * COLS_PER_BLOCK + tid * 4];
        float4 c = *cell;
        c.x += v.x; c.y += v.y; c.z += v.z; c.w += v.w;
        *cell = c;

        const float q = v.x * v.x + v.y * v.y + v.z * v.z + v.w * v.w;
#pragma unroll
        for (int k = 0; k < K_CLS; ++k)
            if (ks == k) s2r[k] += q;   // uniform scalar branch
    }

    // flush S1: each thread reads back only its own cells (no sync needed)
#pragma unroll
    for (int k = 0; k < K_CLS; ++k) {
        const float4 c = *(const float4*)&s1l[k * COLS_PER_BLOCK + tid * 4];
        float* b1 = S1 + k * D_DIM + g * COLS_PER_BLOCK + tid * 4;
        atomicAdd(b1 + 0, c.x); atomicAdd(b1 + 1, c.y);
        atomicAdd(b1 + 2, c.z); atomicAdd(b1 + 3, c.w);
    }

    // flush S2: block-reduce each class, one atomic per (block, class)
#pragma unroll 1
    for (int k = 0; k < K_CLS; ++k) {
        float r = s2r[k];
#pragma unroll
        for (int o = 32; o > 0; o >>= 1) r += __shfl_down(r, o, 64);
        if (lane == 0) wred[wid] = r;
        __syncthreads();
        if (tid == 0) {
            const float t = wred[0] + wred[1] + wred[2] + wred[3];
            if (t != 0.f) atomicAdd(&s2sum[k], t);
        }
        __syncthreads();
    }
}

// Finish: 60 blocks (class k x column-slice g). Counts computed inline.
// Per cell add -S1^2/(cnt^2*D*K); one thread adds S2sum_k/(cnt*D*K).
__global__ __launch_bounds__(256) void wcss_finish(const float* __restrict__ S1,
                                                   const float* __restrict__ s2sum,
                                                   const int* __restrict__ y,
                                                   float* __restrict__ out) {
    __shared__ float sbuf[256];
    const int tid = threadIdx.x;
    const int k = blockIdx.x / NGROUPS;
    const int g = blockIdx.x % NGROUPS;

    int c = 0;
#pragma unroll 4
    for (int i = tid; i < N_SAMP; i += 256) c += (y[i] == k) ? 1 : 0;
    sbuf[tid] = (float)c;
    __syncthreads();
    for (int off = 128; off > 0; off >>= 1) {
        if (tid < off) sbuf[tid] += sbuf[tid + off];
        __syncthreads();
    }
    const float cnt = sbuf[0];
    __syncthreads();

    const float inv = 1.0f / (cnt * cnt * (float)D_DIM * (float)K_CLS);
    const float4 v = *(const float4*)(S1 + k * D_DIM + g * COLS_PER_BLOCK + tid * 4);
    float t = -(v.x * v.x + v.y * v.y + v.z * v.z + v.w * v.w) * inv;
    if (g == 0 && tid == 0)
        t += s2sum[k] / (cnt * (float)D_DIM * (float)K_CLS);

    sbuf[tid] = t;
    __syncthreads();
    for (int off = 128; off > 0; off >>= 1) {
        if (tid < off) sbuf[tid] += sbuf[tid + off];
        __syncthreads();
    }
    if (tid == 0) atomicAdd(out, sbuf[0]);
}

extern "C" void kernel_launch(void* const* d_in, const int* in_sizes, int n_in,
                              void* d_out, int out_size, void* d_ws, size_t ws_size,
                              hipStream_t stream) {
    const float* X = (const float*)d_in[0];
    const int* y = (const int*)d_in[1];

    float* S1 = (float*)d_ws;                       // K*D floats
    float* s2sum = S1 + K_CLS * D_DIM;              // K floats
    float* out = (float*)d_out;

    hipMemsetAsync(S1, 0, (K_CLS * D_DIM + K_CLS) * sizeof(float), stream);
    hipMemsetAsync(out, 0, sizeof(float), stream);

    wcss_accum<<<dim3(NGROUPS, NWIN), dim3(256), 0, stream>>>(X, y, S1, s2sum);
    wcss_finish<<<dim3(K_CLS * NGROUPS), dim3(256), 0, stream>>>(S1, s2sum, y, out);
}

// Round 7
// 303.939 us; speedup vs baseline: 1.4009x; 1.4009x over previous
//
#include <hip/hip_runtime.h>

#define N_SAMP 8192
#define D_DIM 6144
#define K_CLS 10
#define CHUNK 64                          // samples per block (natural order)
#define NWIN (N_SAMP / CHUNK)             // 128 windows
#define COLS_PER_BLOCK 1024               // 256 threads * 4 floats
#define NGROUPS (D_DIM / COLS_PER_BLOCK)  // 6 -> grid 768 = exactly 3 blocks/CU
#define PIPE 8                            // outstanding float4 loads per thread
#define ROWB (D_DIM * 4)                  // row stride in bytes

// Natural-order accumulation. Per-class S1 in registers (a1[10] float4) and
// column-reduced S2 in registers (s2r[10]) -- NO LDS traffic in the hot loop
// (R6 lesson: per-sample LDS RMW serializes the load pipeline). Class index is
// block-uniform per sample: readfirstlane -> scalar compare/branch chain, so
// only the matching class's 8 VALU ops execute. 8-deep rotating load pipeline.
// Flush with PLAIN stores to per-window slabs (no atomic RMW amplification).
__global__ __launch_bounds__(256) void wcss_accum(const float* __restrict__ X,
                                                  const int* __restrict__ y,
                                                  float* __restrict__ part,
                                                  float* __restrict__ s2part) {
    __shared__ int ylds[CHUNK];
    __shared__ float s2w[4][K_CLS];
    const int tid = threadIdx.x;
    const int lane = tid & 63;
    const int wid = tid >> 6;
    const int g = blockIdx.x;
    const int w = blockIdx.y;

    if (tid < CHUNK) ylds[tid] = y[w * CHUNK + tid];
    __syncthreads();

    const char* basep = (const char*)(X + (size_t)w * CHUNK * D_DIM
                                      + g * COLS_PER_BLOCK + tid * 4);

    float4 a1[K_CLS];
    float s2r[K_CLS];
#pragma unroll
    for (int k = 0; k < K_CLS; ++k) {
        a1[k] = make_float4(0.f, 0.f, 0.f, 0.f);
        s2r[k] = 0.f;
    }

    float4 buf[PIPE];
#pragma unroll
    for (int j = 0; j < PIPE; ++j)
        buf[j] = *(const float4*)(basep + (size_t)j * ROWB);

    // main: process s in [0, 56), always keeping 8 loads in flight
#pragma unroll 1
    for (int s8 = 0; s8 + PIPE < CHUNK; s8 += PIPE) {
#pragma unroll
        for (int j = 0; j < PIPE; ++j) {
            const float4 v = buf[j];
            buf[j] = *(const float4*)(basep + (size_t)(s8 + PIPE + j) * ROWB);
            const int ks = __builtin_amdgcn_readfirstlane(ylds[s8 + j]);
            const float q = v.x * v.x + v.y * v.y + v.z * v.z + v.w * v.w;
#pragma unroll
            for (int k = 0; k < K_CLS; ++k)
                if (ks == k) {   // scalar compare -> uniform branch
                    a1[k].x += v.x; a1[k].y += v.y;
                    a1[k].z += v.z; a1[k].w += v.w;
                    s2r[k] += q;
                }
        }
    }
    // tail: s in [56, 64)
#pragma unroll
    for (int j = 0; j < PIPE; ++j) {
        const float4 v = buf[j];
        const int ks = __builtin_amdgcn_readfirstlane(ylds[CHUNK - PIPE + j]);
        const float q = v.x * v.x + v.y * v.y + v.z * v.z + v.w * v.w;
#pragma unroll
        for (int k = 0; k < K_CLS; ++k)
            if (ks == k) {
                a1[k].x += v.x; a1[k].y += v.y;
                a1[k].z += v.z; a1[k].w += v.w;
                s2r[k] += q;
            }
    }

    // flush S1: plain coalesced float4 stores into this window's slab
#pragma unroll
    for (int k = 0; k < K_CLS; ++k) {
        float* p = part + ((size_t)w * K_CLS + k) * D_DIM
                        + g * COLS_PER_BLOCK + tid * 4;
        *(float4*)p = a1[k];
    }

    // flush S2: shuffle-reduce each class across the wave, cross-wave via LDS,
    // one plain store per (block, class)
#pragma unroll
    for (int k = 0; k < K_CLS; ++k) {
        float r = s2r[k];
#pragma unroll
        for (int o = 32; o > 0; o >>= 1) r += __shfl_down(r, o, 64);
        if (lane == 0) s2w[wid][k] = r;
    }
    __syncthreads();
    if (tid < K_CLS)
        s2part[((size_t)w * NGROUPS + g) * K_CLS + tid] =
            s2w[0][tid] + s2w[1][tid] + s2w[2][tid] + s2w[3][tid];
}

// Finish: 60 blocks (class k x column-slice g). Sum the 128 window slabs for
// (k, col) -> S1 total; add -S1^2/(cnt^2*D*K). g==0 block also sums s2part
// for its class. Counts computed inline from y.
__global__ __launch_bounds__(256) void wcss_finish(const float* __restrict__ part,
                                                   const float* __restrict__ s2part,
                                                   const int* __restrict__ y,
                                                   float* __restrict__ out) {
    __shared__ float sbuf[256];
    const int tid = threadIdx.x;
    const int k = blockIdx.x / NGROUPS;
    const int g = blockIdx.x % NGROUPS;

    int c = 0;
#pragma unroll 4
    for (int i = tid; i < N_SAMP; i += 256) c += (y[i] == k) ? 1 : 0;
    sbuf[tid] = (float)c;
    __syncthreads();
    for (int off = 128; off > 0; off >>= 1) {
        if (tid < off) sbuf[tid] += sbuf[tid + off];
        __syncthreads();
    }
    const float cnt = sbuf[0];
    __syncthreads();

    const float inv = 1.0f / (cnt * cnt * (float)D_DIM * (float)K_CLS);

    float4 acc = make_float4(0.f, 0.f, 0.f, 0.f);
    const size_t coloff = (size_t)k * D_DIM + g * COLS_PER_BLOCK + tid * 4;
#pragma unroll 4
    for (int w = 0; w < NWIN; ++w) {
        const float4 v = *(const float4*)(part + (size_t)w * K_CLS * D_DIM + coloff);
        acc.x += v.x; acc.y += v.y; acc.z += v.z; acc.w += v.w;
    }
    float t = -(acc.x * acc.x + acc.y * acc.y + acc.z * acc.z + acc.w * acc.w) * inv;

    if (g == 0) {
        const float s2scale = 1.0f / (cnt * (float)D_DIM * (float)K_CLS);
        float s2k = 0.f;
        for (int b = tid; b < NWIN * NGROUPS; b += 256)
            s2k += s2part[(size_t)b * K_CLS + k];
        t += s2k * s2scale;
    }

    sbuf[tid] = t;
    __syncthreads();
    for (int off = 128; off > 0; off >>= 1) {
        if (tid < off) sbuf[tid] += sbuf[tid + off];
        __syncthreads();
    }
    if (tid == 0) atomicAdd(out, sbuf[0]);
}

extern "C" void kernel_launch(void* const* d_in, const int* in_sizes, int n_in,
                              void* d_out, int out_size, void* d_ws, size_t ws_size,
                              hipStream_t stream) {
    const float* X = (const float*)d_in[0];
    const int* y = (const int*)d_in[1];

    float* part = (float*)d_ws;                                  // NWIN*K*D floats
    float* s2part = part + (size_t)NWIN * K_CLS * D_DIM;         // NWIN*6*K floats
    float* out = (float*)d_out;

    hipMemsetAsync(out, 0, sizeof(float), stream);

    wcss_accum<<<dim3(NGROUPS, NWIN), dim3(256), 0, stream>>>(X, y, part, s2part);
    wcss_finish<<<dim3(K_CLS * NGROUPS), dim3(256), 0, stream>>>(part, s2part, y, out);
}